// Round 9
// baseline (641.629 us; speedup 1.0000x reference)
//
#include <hip/hip_runtime.h>

#define NPTS 16384
#define KNN 16
#define HID 64
#define NCLS 10

#define G 16                 // grid cells per axis
#define NCELL (G * G * G)    // 4096
#define RMAX (G - 1)         // max shell radius
#define NSHELL ((2 * RMAX + 1) * (2 * RMAX + 1) * (2 * RMAX + 1))   // 31^3 = 29791

// ---------- shared helpers ----------

// monotone float->u32: ascending uint order == ascending float order
__device__ __forceinline__ unsigned encm(float x) {
    unsigned u = __float_as_uint(x);
    return (u & 0x80000000u) ? ~u : (u | 0x80000000u);
}
__device__ __forceinline__ float decm(unsigned v) {
    return (v & 0x80000000u) ? __uint_as_float(v ^ 0x80000000u) : __uint_as_float(~v);
}

// wave-uniform float -> SGPR
__device__ __forceinline__ float __frfl(float x) {
    return __int_as_float(__builtin_amdgcn_readfirstlane(__float_as_int(x)));
}

// (dist, idx) packed key: ascending u64 order == (d asc, idx asc) — exact tie-break
__device__ __forceinline__ unsigned long long dkey(float v, unsigned j) {
    return ((unsigned long long)encm(v) << 32) | j;
}

__device__ __forceinline__ unsigned long long shfl_xor_u64(unsigned long long x, int m) {
    unsigned hi = (unsigned)__shfl_xor((int)(x >> 32), m, 64);
    unsigned lo = (unsigned)__shfl_xor((int)(x & 0xffffffffu), m, 64);
    return ((unsigned long long)hi << 32) | lo;
}

// exact wave-wide top-16 from per-lane sorted top-16 lists (proven R0-R8 path)
__device__ __forceinline__ void wave_top16_16(unsigned long long (&key)[16], int lane,
                                              int q, int* __restrict__ idx) {
    int outj = 0x7fffffff;
    for (int r = 0; r < 16; ++r) {
        unsigned long long gm = key[0];
#pragma unroll
        for (int s = 1; s < 16; ++s) gm = key[s] < gm ? key[s] : gm;
#pragma unroll
        for (int st = 1; st < 64; st <<= 1) {
            unsigned long long o = shfl_xor_u64(gm, st);
            gm = o < gm ? o : gm;
        }
        if (lane == r) outj = (int)(gm & 0xffffffffu);
#pragma unroll
        for (int s = 0; s < 16; ++s)
            if (key[s] == gm) key[s] = ~0ull;
    }
    if (lane < 16) idx[q * KNN + lane] = outj;
}

// cell index composition — single definition used by count/scatter/search
__device__ __forceinline__ int cid(int cx, int cy, int cz) { return (cz * G + cy) * G + cx; }

__device__ __forceinline__ int caxis(float x, float lo, float iv) {
    int c = (int)((x - lo) * iv);
    return min(G - 1, max(0, c));
}

// ---------- binning infrastructure ----------

// exact bounding box via monotone-uint atomics (wave-reduced)
__global__ void bbox_kernel(const float* __restrict__ pos, unsigned* __restrict__ bb) {
    int i = blockIdx.x * 256 + threadIdx.x;
    unsigned ex = encm(pos[3 * i]), ey = encm(pos[3 * i + 1]), ez = encm(pos[3 * i + 2]);
    unsigned mnx = ex, mny = ey, mnz = ez, mxx = ex, mxy = ey, mxz = ez;
#pragma unroll
    for (int m = 1; m < 64; m <<= 1) {
        mnx = min(mnx, (unsigned)__shfl_xor((int)mnx, m, 64));
        mny = min(mny, (unsigned)__shfl_xor((int)mny, m, 64));
        mnz = min(mnz, (unsigned)__shfl_xor((int)mnz, m, 64));
        mxx = max(mxx, (unsigned)__shfl_xor((int)mxx, m, 64));
        mxy = max(mxy, (unsigned)__shfl_xor((int)mxy, m, 64));
        mxz = max(mxz, (unsigned)__shfl_xor((int)mxz, m, 64));
    }
    if ((threadIdx.x & 63) == 0) {
        atomicMin(bb + 0, mnx); atomicMin(bb + 1, mny); atomicMin(bb + 2, mnz);
        atomicMax(bb + 3, mxx); atomicMax(bb + 4, mxy); atomicMax(bb + 5, mxz);
    }
}

// per-cell counts + pos4 = (x,y,z,|p|^2) for the EC pipeline
__global__ void count_kernel(const float* __restrict__ pos, const unsigned* __restrict__ bb,
                             float4* __restrict__ pos4, unsigned* __restrict__ cellCnt) {
    int i = blockIdx.x * 256 + threadIdx.x;
    float x = pos[3 * i], y = pos[3 * i + 1], z = pos[3 * i + 2];
    pos4[i] = make_float4(x, y, z, fmaf(x, x, fmaf(y, y, z * z)));
    float lox = decm(bb[0]), loy = decm(bb[1]), loz = decm(bb[2]);
    float sx = decm(bb[3]) - lox, sy = decm(bb[4]) - loy, sz = decm(bb[5]) - loz;
    float ivx = sx > 0.f ? (float)G / sx : 0.f;
    float ivy = sy > 0.f ? (float)G / sy : 0.f;
    float ivz = sz > 0.f ? (float)G / sz : 0.f;
    int c = cid(caxis(x, lox, ivx), caxis(y, loy, ivy), caxis(z, loz, ivz));
    atomicAdd(&cellCnt[c], 1u);
}

// exclusive prefix over 4096 cells: 1 block, 256 threads x 16 cells
__global__ __launch_bounds__(256) void scan_kernel(const unsigned* __restrict__ cellCnt,
                                                   unsigned* __restrict__ cellStart) {
    __shared__ unsigned ps[256];
    int tid = threadIdx.x;
    int base = tid * 16;
    unsigned loc[16];
    unsigned sum = 0;
#pragma unroll
    for (int k = 0; k < 16; ++k) { loc[k] = cellCnt[base + k]; sum += loc[k]; }
    ps[tid] = sum;
    __syncthreads();
    for (int off = 1; off < 256; off <<= 1) {
        unsigned v = (tid >= off) ? ps[tid - off] : 0u;
        __syncthreads();
        ps[tid] += v;
        __syncthreads();
    }
    unsigned run = ps[tid] - sum;          // exclusive prefix of this chunk
#pragma unroll
    for (int k = 0; k < 16; ++k) { cellStart[base + k] = run; run += loc[k]; }
    if (tid == 255) cellStart[NCELL] = run;
}

// scatter points into cell-contiguous storage: binned = (x,y,z, idx-as-bits)
__global__ void scatter_kernel(const float* __restrict__ pos, const unsigned* __restrict__ bb,
                               const unsigned* __restrict__ cellStart,
                               unsigned* __restrict__ cellFill, float4* __restrict__ binned) {
    int i = blockIdx.x * 256 + threadIdx.x;
    float x = pos[3 * i], y = pos[3 * i + 1], z = pos[3 * i + 2];
    float lox = decm(bb[0]), loy = decm(bb[1]), loz = decm(bb[2]);
    float sx = decm(bb[3]) - lox, sy = decm(bb[4]) - loy, sz = decm(bb[5]) - loz;
    float ivx = sx > 0.f ? (float)G / sx : 0.f;
    float ivy = sy > 0.f ? (float)G / sy : 0.f;
    float ivz = sz > 0.f ? (float)G / sz : 0.f;
    int c = cid(caxis(x, lox, ivx), caxis(y, loy, ivy), caxis(z, loz, ivz));
    unsigned slot = cellStart[c] + atomicAdd(&cellFill[c], 1u);
    binned[slot] = make_float4(x, y, z, __uint_as_float((unsigned)i));
}

// shell-offset table: entries for shell r occupy [(2r-1)^3, (2r+1)^3)
__global__ void shelltab_kernel(unsigned* __restrict__ tab, unsigned* __restrict__ fill) {
    int e = blockIdx.x * 256 + threadIdx.x;
    if (e >= NSHELL) return;
    int dz = e / (31 * 31) - 15;
    int dy = (e / 31) % 31 - 15;
    int dx = e % 31 - 15;
    int adx = abs(dx), ady = abs(dy), adz = abs(dz);
    int r = max(adx, max(ady, adz));
    int base = r ? (2 * r - 1) * (2 * r - 1) * (2 * r - 1) : 0;
    int slot = base + (int)atomicAdd(&fill[r], 1u);
    tab[slot] = (unsigned)(dx + 16) | ((unsigned)(dy + 16) << 6) | ((unsigned)(dz + 16) << 12);
}

// ---------- exact grid kNN search: 1 wave = 1 query ----------
// Per-lane sorted top-16 over shell candidates; stop when >=16 kept keys lie
// strictly inside the unreachable-boundary distance (or whole grid searched).
__global__ __launch_bounds__(256) void search_kernel(const float4* __restrict__ pos4,
                                                     const unsigned* __restrict__ bb,
                                                     const unsigned* __restrict__ cellStart,
                                                     const float4* __restrict__ binned,
                                                     const unsigned* __restrict__ shellTab,
                                                     int* __restrict__ idx) {
    int lane = threadIdx.x & 63;
    int w = threadIdx.x >> 6;
    int qi = blockIdx.x * 4 + w;
    float4 qp = pos4[qi];
    float qx = __frfl(qp.x), qy = __frfl(qp.y), qz = __frfl(qp.z);

    float lox = decm(bb[0]), loy = decm(bb[1]), loz = decm(bb[2]);
    float sx = decm(bb[3]) - lox, sy = decm(bb[4]) - loy, sz = decm(bb[5]) - loz;
    float hx = sx / (float)G, hy = sy / (float)G, hz = sz / (float)G;
    float ivx = sx > 0.f ? (float)G / sx : 0.f;
    float ivy = sy > 0.f ? (float)G / sy : 0.f;
    float ivz = sz > 0.f ? (float)G / sz : 0.f;
    int cx = caxis(qx, lox, ivx), cy = caxis(qy, loy, ivy), cz = caxis(qz, loz, ivz);

    unsigned long long key[16];
#pragma unroll
    for (int u = 0; u < 16; ++u) key[u] = ~0ull;

    for (int r = 0; r <= RMAX; ++r) {
        int e0 = r ? (2 * r - 1) * (2 * r - 1) * (2 * r - 1) : 0;
        int e1 = (2 * r + 1) * (2 * r + 1) * (2 * r + 1);
        for (int e = e0; e < e1; ++e) {                 // wave-uniform scalar loop
            unsigned pe = shellTab[e];
            int bx = cx + (int)(pe & 63u) - 16;
            int by = cy + (int)((pe >> 6) & 63u) - 16;
            int bz = cz + (int)((pe >> 12) & 63u) - 16;
            if ((unsigned)bx >= (unsigned)G || (unsigned)by >= (unsigned)G ||
                (unsigned)bz >= (unsigned)G) continue;
            int c = cid(bx, by, bz);
            unsigned s = cellStart[c], t = cellStart[c + 1];
            for (unsigned j = s + (unsigned)lane; j < t; j += 64u) {
                float4 b = binned[j];
                float dx = b.x - qx, dy = b.y - qy, dz = b.z - qz;
                float d = fmaf(dz, dz, fmaf(dy, dy, dx * dx));
                unsigned long long k = dkey(d, __float_as_uint(b.w));
                if (k < key[15]) {
#pragma unroll
                    for (int u = 0; u < 16; ++u) {
                        unsigned long long a = k < key[u] ? k : key[u];
                        unsigned long long bmx = k < key[u] ? key[u] : k;
                        key[u] = a;
                        k = bmx;
                    }
                }
            }
        }
        // termination: all unseen points are beyond the searched box
        bool lcx = (cx - r) <= 0, rcx = (cx + r) >= G - 1;
        bool lcy = (cy - r) <= 0, rcy = (cy + r) >= G - 1;
        bool lcz = (cz - r) <= 0, rcz = (cz + r) >= G - 1;
        if (lcx && rcx && lcy && rcy && lcz && rcz) break;   // whole grid seen
        float dmin = 1e30f;
        if (!lcx) dmin = fminf(dmin, qx - (lox + (float)(cx - r) * hx));
        if (!rcx) dmin = fminf(dmin, (lox + (float)(cx + r + 1) * hx) - qx);
        if (!lcy) dmin = fminf(dmin, qy - (loy + (float)(cy - r) * hy));
        if (!rcy) dmin = fminf(dmin, (loy + (float)(cy + r + 1) * hy) - qy);
        if (!lcz) dmin = fminf(dmin, qz - (loz + (float)(cz - r) * hz));
        if (!rcz) dmin = fminf(dmin, (loz + (float)(cz + r + 1) * hz) - qz);
        float dp = dmin - 1e-4f;                        // fp-rounding guard
        if (dp > 0.f) {
            float thr = dp * dp;
            unsigned long long TK = ((unsigned long long)encm(thr) << 32) | 0xffffffffull;
            int c16 = 0;
#pragma unroll
            for (int u = 0; u < 16; ++u) c16 += (int)(key[u] <= TK);
#pragma unroll
            for (int m = 1; m < 64; m <<= 1) c16 += __shfl_xor(c16, m, 64);
            if (c16 >= KNN) break;   // >=16 points provably closer than any unseen
        }
    }
    wave_top16_16(key, lane, qi, idx);
}

// ---------- EC pipeline (unchanged, proven) ----------

// FUSED EdgeConv1 + ec2_pre (both pointwise in p; h1 never touches global).
__global__ __launch_bounds__(256) void ec12_kernel(const float4* __restrict__ pos4,
                                                   const int* __restrict__ idx,
                                                   const float* __restrict__ W1,
                                                   const float* __restrict__ b1,
                                                   const float* __restrict__ W2,
                                                   const float* __restrict__ b2,
                                                   float* __restrict__ C2,
                                                   float* __restrict__ Y2) {
    __shared__ float h1s[16][64];    // 4KB, [w*4+i][t], wave-private slices
    int t = threadIdx.x & 63;
    int w = threadIdx.x >> 6;
    int pb = blockIdx.x * 16 + w * 4;
    float w0 = W1[0 * HID + t], w1 = W1[1 * HID + t], w2 = W1[2 * HID + t];
    float v0 = W1[3 * HID + t], v1 = W1[4 * HID + t], v2 = W1[5 * HID + t];
    float bt1 = b1[t];
#pragma unroll
    for (int i = 0; i < 4; ++i) {
        int p = pb + i;
        float4 xi = pos4[p];
        float C = bt1 + xi.x * (w0 - v0) + xi.y * (w1 - v1) + xi.z * (w2 - v2);
        const int4* ip = (const int4*)(idx + (size_t)p * KNN);
        int4 n0 = ip[0], n1 = ip[1], n2 = ip[2], n3 = ip[3];   // 4 parallel loads
        int jj[16] = {n0.x, n0.y, n0.z, n0.w, n1.x, n1.y, n1.z, n1.w,
                      n2.x, n2.y, n2.z, n2.w, n3.x, n3.y, n3.z, n3.w};
        float m = -INFINITY;
#pragma unroll
        for (int k = 0; k < KNN; ++k) {
            float4 xj = pos4[jj[k]];      // 16 mutually-independent uniform loads
            m = fmaxf(m, fmaf(xj.x, v0, fmaf(xj.y, v1, xj.z * v2)));
        }
        h1s[w * 4 + i][t] = fmaxf(C + m, 0.f);
    }
    __syncthreads();
    float aa[4] = {0.f, 0.f, 0.f, 0.f};
    float ab[4] = {0.f, 0.f, 0.f, 0.f};
#pragma unroll 8
    for (int f = 0; f < 64; ++f) {
        float wa = W2[f * HID + t];
        float wb = W2[(64 + f) * HID + t];
#pragma unroll
        for (int i = 0; i < 4; ++i) {
            float h = h1s[w * 4 + i][f];   // broadcast ds_read
            aa[i] = fmaf(h, wa, aa[i]);
            ab[i] = fmaf(h, wb, ab[i]);
        }
    }
    float bt = b2[t];
#pragma unroll
    for (int i = 0; i < 4; ++i) {
        C2[(pb + i) * HID + t] = bt + aa[i] - ab[i];
        Y2[(pb + i) * HID + t] = ab[i];
    }
}

// ec2_maxpool: val = relu(C2 + max_k Y2[idx[k]]); block-partial max-pool.
__global__ __launch_bounds__(256) void ec2_maxpool_kernel(const float* __restrict__ C2,
                                                          const float* __restrict__ Y2,
                                                          const int* __restrict__ idx,
                                                          float* __restrict__ gpartial) {
    int t = threadIdx.x & 63;
    int lp = threadIdx.x >> 6;
    int p = blockIdx.x * 4 + lp;
    const int4* ip = (const int4*)(idx + (size_t)p * KNN);
    int4 n0 = ip[0], n1 = ip[1], n2 = ip[2], n3 = ip[3];
    int jj[16] = {n0.x, n0.y, n0.z, n0.w, n1.x, n1.y, n1.z, n1.w,
                  n2.x, n2.y, n2.z, n2.w, n3.x, n3.y, n3.z, n3.w};
    float m = -INFINITY;
#pragma unroll
    for (int k = 0; k < KNN; ++k) {
        m = fmaxf(m, Y2[jj[k] * HID + t]);   // 16 independent gathers
    }
    float val = fmaxf(C2[p * HID + t] + m, 0.f);
    __shared__ float red[4][64];
    red[lp][t] = val;
    __syncthreads();
    if (lp == 0) {
        float g = fmaxf(fmaxf(red[0][t], red[1][t]), fmaxf(red[2][t], red[3][t]));
        gpartial[blockIdx.x * 64 + t] = g;
    }
}

// greduce2: 4096 -> 256 partial rows, fully coalesced, 256 parallel blocks.
__global__ __launch_bounds__(256) void greduce2_kernel(const float* __restrict__ gpartial,
                                                       float* __restrict__ gp2) {
    __shared__ float red[4][64];
    int f = threadIdx.x & 63;
    int w = threadIdx.x >> 6;
    int r0 = blockIdx.x * 16 + w * 4;
    float m = -INFINITY;
#pragma unroll
    for (int r = 0; r < 4; ++r) m = fmaxf(m, gpartial[(r0 + r) * 64 + f]);
    red[w][f] = m;
    __syncthreads();
    if (w == 0)
        gp2[blockIdx.x * 64 + f] =
            fmaxf(fmaxf(red[0][f], red[1][f]), fmaxf(red[2][f], red[3][f]));
}

// tail2: 256 rows -> g[64], then linear head. One block (cheap now).
__global__ __launch_bounds__(256) void tail2_kernel(const float* __restrict__ gp2,
                                                    const float* __restrict__ Wc,
                                                    const float* __restrict__ bc,
                                                    float* __restrict__ out) {
    __shared__ float red[4][64];
    __shared__ float g[64];
    int f = threadIdx.x & 63;
    int w = threadIdx.x >> 6;
    float m = -INFINITY;
    for (int i = w; i < 256; i += 4) m = fmaxf(m, gp2[i * 64 + f]);
    red[w][f] = m;
    __syncthreads();
    if (w == 0) g[f] = fmaxf(fmaxf(red[0][f], red[1][f]), fmaxf(red[2][f], red[3][f]));
    __syncthreads();
    if (threadIdx.x < NCLS) {
        float a = bc[threadIdx.x];
#pragma unroll
        for (int h = 0; h < HID; ++h) a = fmaf(g[h], Wc[h * NCLS + threadIdx.x], a);
        out[threadIdx.x] = a;
    }
}

extern "C" void kernel_launch(void* const* d_in, const int* in_sizes, int n_in,
                              void* d_out, int out_size, void* d_ws, size_t ws_size,
                              hipStream_t stream) {
    const float* pos = (const float*)d_in[0];
    // d_in[1] = batch (all zeros, num_segments=1) -> unused
    const float* W1 = (const float*)d_in[2];
    const float* b1 = (const float*)d_in[3];
    const float* W2 = (const float*)d_in[4];
    const float* b2 = (const float*)d_in[5];
    const float* Wc = (const float*)d_in[6];
    const float* bc = (const float*)d_in[7];
    float* out = (float*)d_out;

    char* ws = (char*)d_ws;
    size_t o = 0;
    auto alloc = [&](size_t bytes) { size_t r = o; o += (bytes + 255) & ~size_t(255); return r; };
    size_t fm = (size_t)NPTS * HID * 4;
    size_t o_bb = alloc(8 * 4);
    size_t o_cnt = alloc((size_t)(NCELL + 1) * 4);
    size_t o_start = alloc((size_t)(NCELL + 1) * 4);
    size_t o_fill = alloc((size_t)NCELL * 4);
    size_t o_sfill = alloc(16 * 4);
    size_t o_stab = alloc((size_t)NSHELL * 4);
    size_t o_pos4 = alloc((size_t)NPTS * 16);
    size_t o_bin = alloc((size_t)NPTS * 16);
    size_t o_idx = alloc((size_t)NPTS * KNN * 4);
    size_t o_C2 = alloc(fm);
    size_t o_Y2 = alloc(fm);
    size_t o_gp = alloc((size_t)(NPTS / 4) * HID * 4);
    size_t o_gp2 = alloc((size_t)256 * HID * 4);

    unsigned* bb = (unsigned*)(ws + o_bb);
    unsigned* cellCnt = (unsigned*)(ws + o_cnt);
    unsigned* cellStart = (unsigned*)(ws + o_start);
    unsigned* cellFill = (unsigned*)(ws + o_fill);
    unsigned* shellFill = (unsigned*)(ws + o_sfill);
    unsigned* shellTab = (unsigned*)(ws + o_stab);
    float4* pos4 = (float4*)(ws + o_pos4);
    float4* binned = (float4*)(ws + o_bin);
    int* idx = (int*)(ws + o_idx);
    float* C2 = (float*)(ws + o_C2);
    float* Y2 = (float*)(ws + o_Y2);
    float* gp = (float*)(ws + o_gp);
    float* gp2 = (float*)(ws + o_gp2);

    hipMemsetAsync(bb, 0xFF, 12, stream);            // min slots -> 0xFFFFFFFF
    hipMemsetAsync(bb + 3, 0x00, 12, stream);        // max slots -> 0
    hipMemsetAsync(cellCnt, 0, (size_t)NCELL * 4, stream);
    hipMemsetAsync(cellFill, 0, (size_t)NCELL * 4, stream);
    hipMemsetAsync(shellFill, 0, 16 * 4, stream);

    bbox_kernel<<<NPTS / 256, 256, 0, stream>>>(pos, bb);
    count_kernel<<<NPTS / 256, 256, 0, stream>>>(pos, bb, pos4, cellCnt);
    scan_kernel<<<1, 256, 0, stream>>>(cellCnt, cellStart);
    scatter_kernel<<<NPTS / 256, 256, 0, stream>>>(pos, bb, cellStart, cellFill, binned);
    shelltab_kernel<<<(NSHELL + 255) / 256, 256, 0, stream>>>(shellTab, shellFill);
    search_kernel<<<NPTS / 4, 256, 0, stream>>>(pos4, bb, cellStart, binned, shellTab, idx);
    ec12_kernel<<<NPTS / 16, 256, 0, stream>>>(pos4, idx, W1, b1, W2, b2, C2, Y2);
    ec2_maxpool_kernel<<<NPTS / 4, 256, 0, stream>>>(C2, Y2, idx, gp);
    greduce2_kernel<<<256, 256, 0, stream>>>(gp, gp2);
    tail2_kernel<<<1, 256, 0, stream>>>(gp2, Wc, bc, out);
}

// Round 10
// 337.622 us; speedup vs baseline: 1.9004x; 1.9004x over previous
//
#include <hip/hip_runtime.h>

#define NPTS 16384
#define KNN 16
#define HID 64
#define NCLS 10

#define G 16                 // grid cells per axis
#define NCELL (G * G * G)    // 4096
#define RMAX (G - 1)         // max shell radius

// ---------- shared helpers ----------

// monotone float->u32: ascending uint order == ascending float order
__device__ __forceinline__ unsigned encm(float x) {
    unsigned u = __float_as_uint(x);
    return (u & 0x80000000u) ? ~u : (u | 0x80000000u);
}
__device__ __forceinline__ float decm(unsigned v) {
    return (v & 0x80000000u) ? __uint_as_float(v ^ 0x80000000u) : __uint_as_float(~v);
}

// wave-uniform float -> SGPR
__device__ __forceinline__ float __frfl(float x) {
    return __int_as_float(__builtin_amdgcn_readfirstlane(__float_as_int(x)));
}
__device__ __forceinline__ int __irfl(int x) { return __builtin_amdgcn_readfirstlane(x); }

// (dist, idx) packed key: ascending u64 order == (d asc, idx asc) — exact tie-break
__device__ __forceinline__ unsigned long long dkey(float v, unsigned j) {
    return ((unsigned long long)encm(v) << 32) | j;
}

__device__ __forceinline__ unsigned long long shfl_xor_u64(unsigned long long x, int m) {
    unsigned hi = (unsigned)__shfl_xor((int)(x >> 32), m, 64);
    unsigned lo = (unsigned)__shfl_xor((int)(x & 0xffffffffu), m, 64);
    return ((unsigned long long)hi << 32) | lo;
}

// exact wave-wide top-16 from per-lane sorted top-16 lists (proven path)
__device__ __forceinline__ void wave_top16_16(unsigned long long (&key)[16], int lane,
                                              int q, int* __restrict__ idx) {
    int outj = 0x7fffffff;
    for (int r = 0; r < 16; ++r) {
        unsigned long long gm = key[0];
#pragma unroll
        for (int s = 1; s < 16; ++s) gm = key[s] < gm ? key[s] : gm;
#pragma unroll
        for (int st = 1; st < 64; st <<= 1) {
            unsigned long long o = shfl_xor_u64(gm, st);
            gm = o < gm ? o : gm;
        }
        if (lane == r) outj = (int)(gm & 0xffffffffu);
#pragma unroll
        for (int s = 0; s < 16; ++s)
            if (key[s] == gm) key[s] = ~0ull;
    }
    if (lane < 16) idx[q * KNN + lane] = outj;
}

// sorted-insert into per-lane top-16 (fires only when candidate beats key[15])
__device__ __forceinline__ void insert16(unsigned long long (&key)[16], unsigned long long k) {
    if (k < key[15]) {
#pragma unroll
        for (int u = 0; u < 16; ++u) {
            unsigned long long a = k < key[u] ? k : key[u];
            unsigned long long b = k < key[u] ? key[u] : k;
            key[u] = a;
            k = b;
        }
    }
}

// cell index composition — single definition used by count/scatter/search
__device__ __forceinline__ int cid(int cx, int cy, int cz) { return (cz * G + cy) * G + cx; }

__device__ __forceinline__ int caxis(float x, float lo, float iv) {
    int c = (int)((x - lo) * iv);
    return min(G - 1, max(0, c));
}

// ---------- binning infrastructure ----------

// exact bounding box via monotone-uint atomics (wave-reduced)
__global__ void bbox_kernel(const float* __restrict__ pos, unsigned* __restrict__ bb) {
    int i = blockIdx.x * 256 + threadIdx.x;
    unsigned ex = encm(pos[3 * i]), ey = encm(pos[3 * i + 1]), ez = encm(pos[3 * i + 2]);
    unsigned mnx = ex, mny = ey, mnz = ez, mxx = ex, mxy = ey, mxz = ez;
#pragma unroll
    for (int m = 1; m < 64; m <<= 1) {
        mnx = min(mnx, (unsigned)__shfl_xor((int)mnx, m, 64));
        mny = min(mny, (unsigned)__shfl_xor((int)mny, m, 64));
        mnz = min(mnz, (unsigned)__shfl_xor((int)mnz, m, 64));
        mxx = max(mxx, (unsigned)__shfl_xor((int)mxx, m, 64));
        mxy = max(mxy, (unsigned)__shfl_xor((int)mxy, m, 64));
        mxz = max(mxz, (unsigned)__shfl_xor((int)mxz, m, 64));
    }
    if ((threadIdx.x & 63) == 0) {
        atomicMin(bb + 0, mnx); atomicMin(bb + 1, mny); atomicMin(bb + 2, mnz);
        atomicMax(bb + 3, mxx); atomicMax(bb + 4, mxy); atomicMax(bb + 5, mxz);
    }
}

// per-cell counts + pos4 = (x,y,z,|p|^2) for the EC pipeline
__global__ void count_kernel(const float* __restrict__ pos, const unsigned* __restrict__ bb,
                             float4* __restrict__ pos4, unsigned* __restrict__ cellCnt) {
    int i = blockIdx.x * 256 + threadIdx.x;
    float x = pos[3 * i], y = pos[3 * i + 1], z = pos[3 * i + 2];
    pos4[i] = make_float4(x, y, z, fmaf(x, x, fmaf(y, y, z * z)));
    float lox = decm(bb[0]), loy = decm(bb[1]), loz = decm(bb[2]);
    float sx = decm(bb[3]) - lox, sy = decm(bb[4]) - loy, sz = decm(bb[5]) - loz;
    float ivx = sx > 0.f ? (float)G / sx : 0.f;
    float ivy = sy > 0.f ? (float)G / sy : 0.f;
    float ivz = sz > 0.f ? (float)G / sz : 0.f;
    int c = cid(caxis(x, lox, ivx), caxis(y, loy, ivy), caxis(z, loz, ivz));
    atomicAdd(&cellCnt[c], 1u);
}

// exclusive prefix over 4096 cells: 1 block, 256 threads x 16 cells
__global__ __launch_bounds__(256) void scan_kernel(const unsigned* __restrict__ cellCnt,
                                                   unsigned* __restrict__ cellStart) {
    __shared__ unsigned ps[256];
    int tid = threadIdx.x;
    int base = tid * 16;
    unsigned loc[16];
    unsigned sum = 0;
#pragma unroll
    for (int k = 0; k < 16; ++k) { loc[k] = cellCnt[base + k]; sum += loc[k]; }
    ps[tid] = sum;
    __syncthreads();
    for (int off = 1; off < 256; off <<= 1) {
        unsigned v = (tid >= off) ? ps[tid - off] : 0u;
        __syncthreads();
        ps[tid] += v;
        __syncthreads();
    }
    unsigned run = ps[tid] - sum;          // exclusive prefix of this chunk
#pragma unroll
    for (int k = 0; k < 16; ++k) { cellStart[base + k] = run; run += loc[k]; }
    if (tid == 255) cellStart[NCELL] = run;
}

// scatter points into cell-contiguous storage: binned = (x,y,z, idx-as-bits)
__global__ void scatter_kernel(const float* __restrict__ pos, const unsigned* __restrict__ bb,
                               const unsigned* __restrict__ cellStart,
                               unsigned* __restrict__ cellFill, float4* __restrict__ binned) {
    int i = blockIdx.x * 256 + threadIdx.x;
    float x = pos[3 * i], y = pos[3 * i + 1], z = pos[3 * i + 2];
    float lox = decm(bb[0]), loy = decm(bb[1]), loz = decm(bb[2]);
    float sx = decm(bb[3]) - lox, sy = decm(bb[4]) - loy, sz = decm(bb[5]) - loz;
    float ivx = sx > 0.f ? (float)G / sx : 0.f;
    float ivy = sy > 0.f ? (float)G / sy : 0.f;
    float ivz = sz > 0.f ? (float)G / sz : 0.f;
    int c = cid(caxis(x, lox, ivx), caxis(y, loy, ivy), caxis(z, loz, ivz));
    unsigned slot = cellStart[c] + atomicAdd(&cellFill[c], 1u);
    binned[slot] = make_float4(x, y, z, __uint_as_float((unsigned)i));
}

// ---------- exact grid kNN search v2: 1 wave = 1 query, x-RUN iteration ----------
// Queries processed in BINNED order (block-adjacent waves share cells -> L1).
// r<=1 box = 9 contiguous x-runs, bounds batch-loaded; shells r>=2 analytic.
// Per-lane sorted top-16 + proven termination bound; exact merge at the end.
__global__ __launch_bounds__(256) void search_kernel(const unsigned* __restrict__ bb,
                                                     const unsigned* __restrict__ cellStart,
                                                     const float4* __restrict__ binned,
                                                     int* __restrict__ idx) {
    int lane = threadIdx.x & 63;
    int w = threadIdx.x >> 6;
    int qb = blockIdx.x * 4 + w;            // binned-order query slot
    float4 qp = binned[qb];                 // uniform address for the wave
    float qx = __frfl(qp.x), qy = __frfl(qp.y), qz = __frfl(qp.z);
    int qorig = __irfl((int)__float_as_uint(qp.w));

    float lox = decm(bb[0]), loy = decm(bb[1]), loz = decm(bb[2]);
    float sx = decm(bb[3]) - lox, sy = decm(bb[4]) - loy, sz = decm(bb[5]) - loz;
    float hx = sx / (float)G, hy = sy / (float)G, hz = sz / (float)G;
    float ivx = sx > 0.f ? (float)G / sx : 0.f;
    float ivy = sy > 0.f ? (float)G / sy : 0.f;
    float ivz = sz > 0.f ? (float)G / sz : 0.f;
    int cx = __irfl(caxis(qx, lox, ivx));
    int cy = __irfl(caxis(qy, loy, ivy));
    int cz = __irfl(caxis(qz, loz, ivz));

    unsigned long long key[16];
#pragma unroll
    for (int u = 0; u < 16; ++u) key[u] = ~0ull;

    auto scan_range = [&](unsigned s, unsigned e) {
        for (unsigned j = s + (unsigned)lane; j < e; j += 64u) {
            float4 b = binned[j];
            float dx = b.x - qx, dy = b.y - qy, dz = b.z - qz;
            float d = fmaf(dz, dz, fmaf(dy, dy, dx * dx));
            insert16(key, dkey(d, __float_as_uint(b.w)));
        }
    };

    // ---- pass 1: full r<=1 box as 9 x-runs, bounds batch-loaded ----
    {
        int x0 = max(cx - 1, 0), x1 = min(cx + 1, G - 1);
        unsigned rs[9], re[9];
#pragma unroll
        for (int dz = 0; dz < 3; ++dz)
#pragma unroll
            for (int dy = 0; dy < 3; ++dy) {
                int bz = cz + dz - 1, by = cy + dy - 1;
                bool v = (unsigned)bz < (unsigned)G && (unsigned)by < (unsigned)G;
                int cb = cid(x0, v ? by : 0, v ? bz : 0);
                int ce = cid(x1, v ? by : 0, v ? bz : 0);
                unsigned s = cellStart[cb], e = cellStart[ce + 1];
                rs[dz * 3 + dy] = v ? s : 0u;
                re[dz * 3 + dy] = v ? e : 0u;
            }
#pragma unroll
        for (int r9 = 0; r9 < 9; ++r9) scan_range(rs[r9], re[r9]);
    }

    // ---- termination check after radius r; then expand shell-by-shell ----
    bool done = false;
    for (int r = 1; r <= RMAX; ++r) {
        if (r >= 2) {
            // scan shell r only: ring rows full-range, interior rows 2 cells
            int bz0 = max(cz - r, 0), bz1 = min(cz + r, G - 1);
            int by0 = max(cy - r, 0), by1 = min(cy + r, G - 1);
            int xa = max(cx - r, 0), xb = min(cx + r, G - 1);
            for (int bz = bz0; bz <= bz1; ++bz) {
                int adz = abs(bz - cz);
                for (int by = by0; by <= by1; ++by) {
                    int ady = abs(by - cy);
                    if (adz == r || ady == r) {
                        unsigned s = cellStart[cid(xa, by, bz)];
                        unsigned e = cellStart[cid(xb, by, bz) + 1];
                        scan_range(s, e);
                    } else {
                        int xl = cx - r;
                        if (xl >= 0) {
                            int c = cid(xl, by, bz);
                            scan_range(cellStart[c], cellStart[c + 1]);
                        }
                        int xr = cx + r;
                        if (xr <= G - 1) {
                            int c = cid(xr, by, bz);
                            scan_range(cellStart[c], cellStart[c + 1]);
                        }
                    }
                }
            }
        }
        // termination: all unseen points are beyond the searched box
        bool lcx = (cx - r) <= 0, rcx = (cx + r) >= G - 1;
        bool lcy = (cy - r) <= 0, rcy = (cy + r) >= G - 1;
        bool lcz = (cz - r) <= 0, rcz = (cz + r) >= G - 1;
        if (lcx && rcx && lcy && rcy && lcz && rcz) { done = true; break; }
        float dmin = 1e30f;
        if (!lcx) dmin = fminf(dmin, qx - (lox + (float)(cx - r) * hx));
        if (!rcx) dmin = fminf(dmin, (lox + (float)(cx + r + 1) * hx) - qx);
        if (!lcy) dmin = fminf(dmin, qy - (loy + (float)(cy - r) * hy));
        if (!rcy) dmin = fminf(dmin, (loy + (float)(cy + r + 1) * hy) - qy);
        if (!lcz) dmin = fminf(dmin, qz - (loz + (float)(cz - r) * hz));
        if (!rcz) dmin = fminf(dmin, (loz + (float)(cz + r + 1) * hz) - qz);
        float dp = dmin - 1e-4f;                        // fp-rounding guard
        if (dp > 0.f) {
            float thr = dp * dp;
            unsigned long long TK = ((unsigned long long)encm(thr) << 32) | 0xffffffffull;
            int c16 = 0;
#pragma unroll
            for (int u = 0; u < 16; ++u) c16 += (int)(key[u] <= TK);
#pragma unroll
            for (int m = 1; m < 64; m <<= 1) c16 += __shfl_xor(c16, m, 64);
            if (c16 >= KNN) { done = true; break; }
        }
    }
    (void)done;
    wave_top16_16(key, lane, qorig, idx);
}

// ---------- EC pipeline (unchanged, proven) ----------

// FUSED EdgeConv1 + ec2_pre (both pointwise in p; h1 never touches global).
__global__ __launch_bounds__(256) void ec12_kernel(const float4* __restrict__ pos4,
                                                   const int* __restrict__ idx,
                                                   const float* __restrict__ W1,
                                                   const float* __restrict__ b1,
                                                   const float* __restrict__ W2,
                                                   const float* __restrict__ b2,
                                                   float* __restrict__ C2,
                                                   float* __restrict__ Y2) {
    __shared__ float h1s[16][64];    // 4KB, [w*4+i][t], wave-private slices
    int t = threadIdx.x & 63;
    int w = threadIdx.x >> 6;
    int pb = blockIdx.x * 16 + w * 4;
    float w0 = W1[0 * HID + t], w1 = W1[1 * HID + t], w2 = W1[2 * HID + t];
    float v0 = W1[3 * HID + t], v1 = W1[4 * HID + t], v2 = W1[5 * HID + t];
    float bt1 = b1[t];
#pragma unroll
    for (int i = 0; i < 4; ++i) {
        int p = pb + i;
        float4 xi = pos4[p];
        float C = bt1 + xi.x * (w0 - v0) + xi.y * (w1 - v1) + xi.z * (w2 - v2);
        const int4* ip = (const int4*)(idx + (size_t)p * KNN);
        int4 n0 = ip[0], n1 = ip[1], n2 = ip[2], n3 = ip[3];   // 4 parallel loads
        int jj[16] = {n0.x, n0.y, n0.z, n0.w, n1.x, n1.y, n1.z, n1.w,
                      n2.x, n2.y, n2.z, n2.w, n3.x, n3.y, n3.z, n3.w};
        float m = -INFINITY;
#pragma unroll
        for (int k = 0; k < KNN; ++k) {
            float4 xj = pos4[jj[k]];      // 16 mutually-independent uniform loads
            m = fmaxf(m, fmaf(xj.x, v0, fmaf(xj.y, v1, xj.z * v2)));
        }
        h1s[w * 4 + i][t] = fmaxf(C + m, 0.f);
    }
    __syncthreads();
    float aa[4] = {0.f, 0.f, 0.f, 0.f};
    float ab[4] = {0.f, 0.f, 0.f, 0.f};
#pragma unroll 8
    for (int f = 0; f < 64; ++f) {
        float wa = W2[f * HID + t];
        float wb = W2[(64 + f) * HID + t];
#pragma unroll
        for (int i = 0; i < 4; ++i) {
            float h = h1s[w * 4 + i][f];   // broadcast ds_read
            aa[i] = fmaf(h, wa, aa[i]);
            ab[i] = fmaf(h, wb, ab[i]);
        }
    }
    float bt = b2[t];
#pragma unroll
    for (int i = 0; i < 4; ++i) {
        C2[(pb + i) * HID + t] = bt + aa[i] - ab[i];
        Y2[(pb + i) * HID + t] = ab[i];
    }
}

// ec2_maxpool: val = relu(C2 + max_k Y2[idx[k]]); block-partial max-pool.
__global__ __launch_bounds__(256) void ec2_maxpool_kernel(const float* __restrict__ C2,
                                                          const float* __restrict__ Y2,
                                                          const int* __restrict__ idx,
                                                          float* __restrict__ gpartial) {
    int t = threadIdx.x & 63;
    int lp = threadIdx.x >> 6;
    int p = blockIdx.x * 4 + lp;
    const int4* ip = (const int4*)(idx + (size_t)p * KNN);
    int4 n0 = ip[0], n1 = ip[1], n2 = ip[2], n3 = ip[3];
    int jj[16] = {n0.x, n0.y, n0.z, n0.w, n1.x, n1.y, n1.z, n1.w,
                  n2.x, n2.y, n2.z, n2.w, n3.x, n3.y, n3.z, n3.w};
    float m = -INFINITY;
#pragma unroll
    for (int k = 0; k < KNN; ++k) {
        m = fmaxf(m, Y2[jj[k] * HID + t]);   // 16 independent gathers
    }
    float val = fmaxf(C2[p * HID + t] + m, 0.f);
    __shared__ float red[4][64];
    red[lp][t] = val;
    __syncthreads();
    if (lp == 0) {
        float g = fmaxf(fmaxf(red[0][t], red[1][t]), fmaxf(red[2][t], red[3][t]));
        gpartial[blockIdx.x * 64 + t] = g;
    }
}

// greduce2: 4096 -> 256 partial rows, fully coalesced, 256 parallel blocks.
__global__ __launch_bounds__(256) void greduce2_kernel(const float* __restrict__ gpartial,
                                                       float* __restrict__ gp2) {
    __shared__ float red[4][64];
    int f = threadIdx.x & 63;
    int w = threadIdx.x >> 6;
    int r0 = blockIdx.x * 16 + w * 4;
    float m = -INFINITY;
#pragma unroll
    for (int r = 0; r < 4; ++r) m = fmaxf(m, gpartial[(r0 + r) * 64 + f]);
    red[w][f] = m;
    __syncthreads();
    if (w == 0)
        gp2[blockIdx.x * 64 + f] =
            fmaxf(fmaxf(red[0][f], red[1][f]), fmaxf(red[2][f], red[3][f]));
}

// tail2: 256 rows -> g[64], then linear head. One block (cheap now).
__global__ __launch_bounds__(256) void tail2_kernel(const float* __restrict__ gp2,
                                                    const float* __restrict__ Wc,
                                                    const float* __restrict__ bc,
                                                    float* __restrict__ out) {
    __shared__ float red[4][64];
    __shared__ float g[64];
    int f = threadIdx.x & 63;
    int w = threadIdx.x >> 6;
    float m = -INFINITY;
    for (int i = w; i < 256; i += 4) m = fmaxf(m, gp2[i * 64 + f]);
    red[w][f] = m;
    __syncthreads();
    if (w == 0) g[f] = fmaxf(fmaxf(red[0][f], red[1][f]), fmaxf(red[2][f], red[3][f]));
    __syncthreads();
    if (threadIdx.x < NCLS) {
        float a = bc[threadIdx.x];
#pragma unroll
        for (int h = 0; h < HID; ++h) a = fmaf(g[h], Wc[h * NCLS + threadIdx.x], a);
        out[threadIdx.x] = a;
    }
}

extern "C" void kernel_launch(void* const* d_in, const int* in_sizes, int n_in,
                              void* d_out, int out_size, void* d_ws, size_t ws_size,
                              hipStream_t stream) {
    const float* pos = (const float*)d_in[0];
    // d_in[1] = batch (all zeros, num_segments=1) -> unused
    const float* W1 = (const float*)d_in[2];
    const float* b1 = (const float*)d_in[3];
    const float* W2 = (const float*)d_in[4];
    const float* b2 = (const float*)d_in[5];
    const float* Wc = (const float*)d_in[6];
    const float* bc = (const float*)d_in[7];
    float* out = (float*)d_out;

    char* ws = (char*)d_ws;
    size_t o = 0;
    auto alloc = [&](size_t bytes) { size_t r = o; o += (bytes + 255) & ~size_t(255); return r; };
    size_t fm = (size_t)NPTS * HID * 4;
    size_t o_bb = alloc(8 * 4);
    size_t o_cnt = alloc((size_t)(NCELL + 1) * 4);
    size_t o_start = alloc((size_t)(NCELL + 1) * 4);
    size_t o_fill = alloc((size_t)NCELL * 4);
    size_t o_pos4 = alloc((size_t)NPTS * 16);
    size_t o_bin = alloc((size_t)NPTS * 16);
    size_t o_idx = alloc((size_t)NPTS * KNN * 4);
    size_t o_C2 = alloc(fm);
    size_t o_Y2 = alloc(fm);
    size_t o_gp = alloc((size_t)(NPTS / 4) * HID * 4);
    size_t o_gp2 = alloc((size_t)256 * HID * 4);

    unsigned* bb = (unsigned*)(ws + o_bb);
    unsigned* cellCnt = (unsigned*)(ws + o_cnt);
    unsigned* cellStart = (unsigned*)(ws + o_start);
    unsigned* cellFill = (unsigned*)(ws + o_fill);
    float4* pos4 = (float4*)(ws + o_pos4);
    float4* binned = (float4*)(ws + o_bin);
    int* idx = (int*)(ws + o_idx);
    float* C2 = (float*)(ws + o_C2);
    float* Y2 = (float*)(ws + o_Y2);
    float* gp = (float*)(ws + o_gp);
    float* gp2 = (float*)(ws + o_gp2);

    hipMemsetAsync(bb, 0xFF, 12, stream);            // min slots -> 0xFFFFFFFF
    hipMemsetAsync(bb + 3, 0x00, 12, stream);        // max slots -> 0
    hipMemsetAsync(cellCnt, 0, (size_t)NCELL * 4, stream);
    hipMemsetAsync(cellFill, 0, (size_t)NCELL * 4, stream);

    bbox_kernel<<<NPTS / 256, 256, 0, stream>>>(pos, bb);
    count_kernel<<<NPTS / 256, 256, 0, stream>>>(pos, bb, pos4, cellCnt);
    scan_kernel<<<1, 256, 0, stream>>>(cellCnt, cellStart);
    scatter_kernel<<<NPTS / 256, 256, 0, stream>>>(pos, bb, cellStart, cellFill, binned);
    search_kernel<<<NPTS / 4, 256, 0, stream>>>(bb, cellStart, binned, idx);
    ec12_kernel<<<NPTS / 16, 256, 0, stream>>>(pos4, idx, W1, b1, W2, b2, C2, Y2);
    ec2_maxpool_kernel<<<NPTS / 4, 256, 0, stream>>>(C2, Y2, idx, gp);
    greduce2_kernel<<<256, 256, 0, stream>>>(gp, gp2);
    tail2_kernel<<<1, 256, 0, stream>>>(gp2, Wc, bc, out);
}